// Round 3
// baseline (148.637 us; speedup 1.0000x reference)
//
#include <hip/hip_runtime.h>

// Problem constants (from reference setup_inputs)
#define BATCH 256
#define SEQ   2048
#define VOCAB 128000
#define HASH  4096    // 2x SEQ -> load factor 0.5 for linear probing
#define CHUNK 16384   // floats of LDS staging per iteration (64 KB)

typedef float v4f __attribute__((ext_vector_type(4)));   // true vector type
typedef int   v4i __attribute__((ext_vector_type(4)));

// One block per batch row, 256 threads, each thread owns 8 positions:
//   i = 4*t + k        (k=0..3)
//   i = 1024 + 4*t + k (k=0..3)
// Phase 1: softmax (shuffle + LDS reduce), write weights out.
// Phase 2: dedup duplicate tokens via LDS hash (last position wins = numpy
//          fancy-assignment semantics).
// Phase 3: build w_a row in LDS chunks (zero + scatter winners) and stream
//          out with coalesced nontemporal float4 stores — each w_a byte is
//          written to HBM exactly once; no global memset pass.
__global__ __launch_bounds__(256)
void softmax_scatter_fused(const float* __restrict__ w_es,
                           const int*   __restrict__ x,
                           float* __restrict__ w_a,     // [BATCH, VOCAB]
                           float* __restrict__ w_out)   // [BATCH, SEQ]
{
    __shared__ int   key [HASH];    // token id or -1
    __shared__ int   maxi[HASH];    // max position index for this token
    __shared__ float val [CHUNK];   // staging chunk of the w_a row
    __shared__ float red[8];        // [0..3] max partials, [4..7] sum partials

    const int r = blockIdx.x;
    const int t = threadIdx.x;
    const int lane = t & 63;
    const int wid  = t >> 6;        // 4 waves of 64

    // ---- init hash table (barrier before use provided by reduction syncs) ----
    for (int j = t; j < HASH; j += 256) { key[j] = -1; maxi[j] = -1; }

    // ---- load scores, vectorized ----
    const float* rowp = w_es + (size_t)r * SEQ;
    const v4f a0 = ((const v4f*)rowp)[t];
    const v4f a1 = ((const v4f*)rowp)[256 + t];

    // ---- block max ----
    float m = fmaxf(fmaxf(fmaxf(a0.x, a0.y), fmaxf(a0.z, a0.w)),
                    fmaxf(fmaxf(a1.x, a1.y), fmaxf(a1.z, a1.w)));
    #pragma unroll
    for (int off = 32; off > 0; off >>= 1)
        m = fmaxf(m, __shfl_down(m, off, 64));
    if (lane == 0) red[wid] = m;
    __syncthreads();
    m = fmaxf(fmaxf(red[0], red[1]), fmaxf(red[2], red[3]));

    // ---- exp + block sum ----
    float e[8];
    e[0] = __expf(a0.x - m); e[1] = __expf(a0.y - m);
    e[2] = __expf(a0.z - m); e[3] = __expf(a0.w - m);
    e[4] = __expf(a1.x - m); e[5] = __expf(a1.y - m);
    e[6] = __expf(a1.z - m); e[7] = __expf(a1.w - m);
    float s = e[0] + e[1] + e[2] + e[3] + e[4] + e[5] + e[6] + e[7];
    #pragma unroll
    for (int off = 32; off > 0; off >>= 1)
        s += __shfl_down(s, off, 64);
    if (lane == 0) red[4 + wid] = s;
    __syncthreads();
    s = red[4] + red[5] + red[6] + red[7];

    const float inv = 1.0f / s;
    float w[8];
    #pragma unroll
    for (int k = 0; k < 8; ++k) w[k] = e[k] * inv;

    // ---- write weights output (coalesced float4) ----
    float* wrow = w_out + (size_t)r * SEQ;
    v4f w0; w0.x = w[0]; w0.y = w[1]; w0.z = w[2]; w0.w = w[3];
    v4f w1; w1.x = w[4]; w1.y = w[5]; w1.z = w[6]; w1.w = w[7];
    ((v4f*)wrow)[t]       = w0;
    ((v4f*)wrow)[256 + t] = w1;

    // ---- load token ids ----
    const int* xrow = x + (size_t)r * SEQ;
    const v4i x0 = ((const v4i*)xrow)[t];
    const v4i x1 = ((const v4i*)xrow)[256 + t];
    int tok[8] = { x0.x, x0.y, x0.z, x0.w, x1.x, x1.y, x1.z, x1.w };
    int idx[8];
    #pragma unroll
    for (int k = 0; k < 4; ++k) { idx[k] = 4 * t + k; idx[4 + k] = 1024 + 4 * t + k; }

    // ---- dedup via LDS hash: claim slot with CAS, track max position ----
    // Slots are write-once, so every holder of token T converges to the same
    // slot (first slot in T's probe sequence that contains T).
    int slot[8];
    #pragma unroll
    for (int k = 0; k < 8; ++k) {
        unsigned h = (((unsigned)tok[k] * 2654435761u) >> 16) & (HASH - 1);
        int sl = (int)h;
        while (true) {
            int prev = atomicCAS(&key[sl], -1, tok[k]);
            if (prev == -1 || prev == tok[k]) break;
            sl = (sl + 1) & (HASH - 1);
        }
        slot[k] = sl;
        atomicMax(&maxi[sl], idx[k]);
    }
    __syncthreads();

    // winner flag: the max-position holder of each distinct token
    bool win[8];
    #pragma unroll
    for (int k = 0; k < 8; ++k) win[k] = (maxi[slot[k]] == idx[k]);

    // ---- build the w_a row chunk-by-chunk in LDS, stream out once ----
    float* warow = w_a + (size_t)r * VOCAB;
    const v4f z4 = (v4f)0.0f;

    for (int base = 0; base < VOCAB; base += CHUNK) {
        const int cnt  = (VOCAB - base < CHUNK) ? (VOCAB - base) : CHUNK;
        const int cnt4 = cnt >> 2;   // 4096 or 3328 — both divisible by 256

        // zero the staging chunk
        for (int j = t; j < cnt4; j += 256)
            ((v4f*)val)[j] = z4;
        __syncthreads();

        // scatter winners that fall in [base, base+cnt)
        #pragma unroll
        for (int k = 0; k < 8; ++k) {
            int v = tok[k] - base;
            if (win[k] && (unsigned)v < (unsigned)cnt)
                val[v] = w[k];
        }
        __syncthreads();

        // stream chunk to global, coalesced nontemporal float4
        float* gp = warow + base;
        for (int j = t; j < cnt4; j += 256) {
            v4f v4 = ((const v4f*)val)[j];
            __builtin_nontemporal_store(v4, (v4f*)(gp + 4 * j));
        }
        __syncthreads();   // val reads complete before next-iter zeroing
    }
}

extern "C" void kernel_launch(void* const* d_in, const int* in_sizes, int n_in,
                              void* d_out, int out_size, void* d_ws, size_t ws_size,
                              hipStream_t stream) {
    const float* w_es = (const float*)d_in[0];
    const int*   x    = (const int*)d_in[1];

    float* out  = (float*)d_out;
    float* w_a  = out;                          // [256, 128000]
    float* w    = out + (size_t)BATCH * VOCAB;  // [256, 2048]

    softmax_scatter_fused<<<BATCH, 256, 0, stream>>>(w_es, x, w_a, w);
}

// Round 4
// 142.577 us; speedup vs baseline: 1.0425x; 1.0425x over previous
//
#include <hip/hip_runtime.h>

// Problem constants (from reference setup_inputs)
#define BATCH 256
#define SEQ   2048
#define VOCAB 128000
#define CHUNK 16384              // floats of w_a staged per block (64 KB LDS)
#define CPR   8                  // chunks per row: ceil(128000/16384) = 8

typedef float v4f __attribute__((ext_vector_type(4)));
typedef int   v4i __attribute__((ext_vector_type(4)));

// Grid = BATCH * CPR blocks. Block (r, c) redundantly computes row r's softmax
// (8 KB re-read, trivial) and owns w_a[r, c*CHUNK : c*CHUNK+cnt].
//
// Dedup without a hash (numpy last-write-wins):
//   LDS chunk as int, init -1.
//   pass1: atomicMax(chunk[tok-base], position_idx)   -- only in-range tokens
//   pass2: holder with chunk[v]==idx writes f32 weight (sign bit 0 => >=0)
//   pass3: stream out; bits<0 means "no token here" -> 0.0f
// Every w_a byte goes to HBM exactly once, coalesced float4.
__global__ __launch_bounds__(256)
void softmax_scatter_chunked(const float* __restrict__ w_es,
                             const int*   __restrict__ x,
                             float* __restrict__ w_a,     // [BATCH, VOCAB]
                             float* __restrict__ w_out)   // [BATCH, SEQ]
{
    __shared__ int   chunk[CHUNK];
    __shared__ float red[8];       // [0..3] max partials, [4..7] sum partials

    const int bid = blockIdx.x;
    const int r = bid >> 3;        // row
    const int c = bid & (CPR - 1); // chunk index within row
    const int base = c * CHUNK;
    const int cnt  = (VOCAB - base < CHUNK) ? (VOCAB - base) : CHUNK; // 16384 or 13312
    const int cnt4 = cnt >> 2;     // 4096 or 3328, both divisible by 256

    const int t = threadIdx.x;
    const int lane = t & 63;
    const int wid  = t >> 6;

    // ---- init chunk to -1 (int4) ----
    {
        const v4i m1 = (v4i)(-1);
        for (int j = t; j < cnt4; j += 256)
            ((v4i*)chunk)[j] = m1;
    }

    // ---- load scores, vectorized: positions 4t+k and 1024+4t+k ----
    const float* rowp = w_es + (size_t)r * SEQ;
    const v4f a0 = ((const v4f*)rowp)[t];
    const v4f a1 = ((const v4f*)rowp)[256 + t];

    // ---- block max ----
    float m = fmaxf(fmaxf(fmaxf(a0.x, a0.y), fmaxf(a0.z, a0.w)),
                    fmaxf(fmaxf(a1.x, a1.y), fmaxf(a1.z, a1.w)));
    #pragma unroll
    for (int off = 32; off > 0; off >>= 1)
        m = fmaxf(m, __shfl_down(m, off, 64));
    if (lane == 0) red[wid] = m;
    __syncthreads();               // also covers chunk init visibility
    m = fmaxf(fmaxf(red[0], red[1]), fmaxf(red[2], red[3]));

    // ---- exp + block sum ----
    float e[8];
    e[0] = __expf(a0.x - m); e[1] = __expf(a0.y - m);
    e[2] = __expf(a0.z - m); e[3] = __expf(a0.w - m);
    e[4] = __expf(a1.x - m); e[5] = __expf(a1.y - m);
    e[6] = __expf(a1.z - m); e[7] = __expf(a1.w - m);
    float s = e[0] + e[1] + e[2] + e[3] + e[4] + e[5] + e[6] + e[7];
    #pragma unroll
    for (int off = 32; off > 0; off >>= 1)
        s += __shfl_down(s, off, 64);
    if (lane == 0) red[4 + wid] = s;
    __syncthreads();
    s = red[4] + red[5] + red[6] + red[7];

    const float inv = 1.0f / s;
    float w[8];
    #pragma unroll
    for (int k = 0; k < 8; ++k) w[k] = 0.0f;
    w[0] = e[0] * inv; w[1] = e[1] * inv; w[2] = e[2] * inv; w[3] = e[3] * inv;
    w[4] = e[4] * inv; w[5] = e[5] * inv; w[6] = e[6] * inv; w[7] = e[7] * inv;

    // ---- chunk 0's block also writes the weights output ----
    if (c == 0) {
        float* wrow = w_out + (size_t)r * SEQ;
        v4f w0; w0.x = w[0]; w0.y = w[1]; w0.z = w[2]; w0.w = w[3];
        v4f w1; w1.x = w[4]; w1.y = w[5]; w1.z = w[6]; w1.w = w[7];
        ((v4f*)wrow)[t]       = w0;
        ((v4f*)wrow)[256 + t] = w1;
    }

    // ---- load token ids ----
    const int* xrow = x + (size_t)r * SEQ;
    const v4i x0 = ((const v4i*)xrow)[t];
    const v4i x1 = ((const v4i*)xrow)[256 + t];
    int tok[8] = { x0.x, x0.y, x0.z, x0.w, x1.x, x1.y, x1.z, x1.w };
    int idx[8];
    #pragma unroll
    for (int k = 0; k < 4; ++k) { idx[k] = 4 * t + k; idx[4 + k] = 1024 + 4 * t + k; }

    // relative position within this chunk; flag in-range tokens
    int v[8]; bool inr[8];
    #pragma unroll
    for (int k = 0; k < 8; ++k) {
        v[k] = tok[k] - base;
        inr[k] = (unsigned)v[k] < (unsigned)cnt;
    }

    // ---- pass 1: max position index per hit slot ----
    #pragma unroll
    for (int k = 0; k < 8; ++k)
        if (inr[k]) atomicMax(&chunk[v[k]], idx[k]);
    __syncthreads();

    // ---- pass 2: winner writes its weight (f32 bits, sign >= 0) ----
    #pragma unroll
    for (int k = 0; k < 8; ++k)
        if (inr[k] && chunk[v[k]] == idx[k])
            ((float*)chunk)[v[k]] = w[k];
    __syncthreads();

    // ---- pass 3: stream chunk to global; negative bits => empty => 0 ----
    float* gp = w_a + (size_t)r * VOCAB + base;
    for (int j = t; j < cnt4; j += 256) {
        v4i b = ((const v4i*)chunk)[j];
        v4f o;
        o.x = (b.x < 0) ? 0.0f : __int_as_float(b.x);
        o.y = (b.y < 0) ? 0.0f : __int_as_float(b.y);
        o.z = (b.z < 0) ? 0.0f : __int_as_float(b.z);
        o.w = (b.w < 0) ? 0.0f : __int_as_float(b.w);
        ((v4f*)(gp))[j] = o;
    }
}

extern "C" void kernel_launch(void* const* d_in, const int* in_sizes, int n_in,
                              void* d_out, int out_size, void* d_ws, size_t ws_size,
                              hipStream_t stream) {
    const float* w_es = (const float*)d_in[0];
    const int*   x    = (const int*)d_in[1];

    float* out  = (float*)d_out;
    float* w_a  = out;                          // [256, 128000]
    float* w    = out + (size_t)BATCH * VOCAB;  // [256, 2048]

    softmax_scatter_chunked<<<BATCH * CPR, 256, 0, stream>>>(w_es, x, w_a, w);
}